// Round 3
// baseline (378.208 us; speedup 1.0000x reference)
//
#include <hip/hip_runtime.h>

// binning_CRVD forward: out[b,c,hw] = sum_j P[c/4][j] * x[b, j*16 + c, hw]
// B=16, C_in=64, C_out=16, H=W=256. Pure streaming, memory-bound.
// Group order along c/4: gb (0-3), b (4-7), r (8-11), gr (12-15).

constexpr int HW   = 256 * 256;   // 65536 elements per plane
constexpr int HW4  = HW / 4;      // 16384 float4 per plane
constexpr int LOG2_HW4 = 14;

__global__ __launch_bounds__(256)
void binning_CRVD_kernel(const float4* __restrict__ x,
                         const float*  __restrict__ pgb,
                         const float*  __restrict__ pb,
                         const float*  __restrict__ pr,
                         const float*  __restrict__ pgr,
                         float4* __restrict__ out,
                         int total4)
{
    const int stride = gridDim.x * blockDim.x;
    for (int idx = blockIdx.x * blockDim.x + threadIdx.x; idx < total4; idx += stride) {
        const int hw = idx & (HW4 - 1);
        const int bc = idx >> LOG2_HW4;     // b*16 + c
        const int c  = bc & 15;
        const int b  = bc >> 4;

        // pick the group's 4-tap weight vector (uniform within a wave:
        // 256-thread blocks never straddle a (b,c) plane of 16384 float4s)
        const float* p = (c < 8) ? ((c < 4) ? pgb : pb)
                                 : ((c < 12) ? pr : pgr);
        const float w0 = p[0], w1 = p[1], w2 = p[2], w3 = p[3];

        const float4* xp = x + (((size_t)b * 64 + c) << LOG2_HW4) + hw;
        const float4 t0 = xp[0 * 16 * HW4];
        const float4 t1 = xp[1 * 16 * HW4];
        const float4 t2 = xp[2 * 16 * HW4];
        const float4 t3 = xp[3 * 16 * HW4];

        float4 o;
        o.x = w0 * t0.x + w1 * t1.x + w2 * t2.x + w3 * t3.x;
        o.y = w0 * t0.y + w1 * t1.y + w2 * t2.y + w3 * t3.y;
        o.z = w0 * t0.z + w1 * t1.z + w2 * t2.z + w3 * t3.z;
        o.w = w0 * t0.w + w1 * t1.w + w2 * t2.w + w3 * t3.w;
        out[idx] = o;
    }
}

extern "C" void kernel_launch(void* const* d_in, const int* in_sizes, int n_in,
                              void* d_out, int out_size, void* d_ws, size_t ws_size,
                              hipStream_t stream)
{
    const float4* x   = (const float4*)d_in[0];
    const float*  pgb = (const float*)d_in[1];
    const float*  pb  = (const float*)d_in[2];
    const float*  pr  = (const float*)d_in[3];
    const float*  pgr = (const float*)d_in[4];
    float* out = (float*)d_out;

    const int total4 = out_size / 4;          // 16*16*65536/4 = 4,194,304
    const int threads = 256;
    const int blocks  = 4096;                 // grid-stride, 4 iters/thread

    binning_CRVD_kernel<<<blocks, threads, 0, stream>>>(
        x, pgb, pb, pr, pgr, (float4*)out, total4);
}